// Round 11
// baseline (489.343 us; speedup 1.0000x reference)
//
#include <hip/hip_runtime.h>

// SpeakerCrossAttention on MI355X (gfx950) — v11: A-in-registers persistent pipeline.
// B=16, D=512, T=8192, S=256. f32 in/out; GEMM in bf16 MFMA.
//
// Root cause after v10: per-tile L2 re-read of the full 512KB W1f (A) inside the
// barrier-fenced GEMM phase (~3.8us/tile, 8x the feature traffic). Fix: A lives
// in VGPRs. 8 waves x 64n: af[4][16] short8 = 256 VGPR/lane, loaded once per
// block. GEMM phase = pure LDS+MFMA. Features stream via global_load_lds DMA
// (counted vmcnt(32), never drained); out via plain stores. 1 block/CU, 16
// tiles of 32t. LDS: F 64KB (single) + Bt 32KB + attn/gpart/alpha ~ 101KB.

typedef __attribute__((ext_vector_type(8))) short short8;     // 8 bf16 = 16B
typedef __attribute__((ext_vector_type(4))) float f32x4;

#define T_DIM 8192
#define D_DIM 512

__device__ __forceinline__ unsigned short f2bf(float x) {  // RTNE f32 -> bf16
  unsigned u = __builtin_bit_cast(unsigned, x);
  u = (u + 0x7fffu + ((u >> 16) & 1u)) >> 16;
  return (unsigned short)u;
}
__device__ __forceinline__ float bf2f(unsigned short h) {
  return __builtin_bit_cast(float, ((unsigned)h) << 16);
}
__device__ __forceinline__ void dma16(const void* g, void* l) {
  __builtin_amdgcn_global_load_lds(
      (const __attribute__((address_space(1))) void*)g,
      (__attribute__((address_space(3))) void*)l, 16, 0, 0);
}

// ---------------- prep kernel ----------------
// blocks 0..15: per-batch chain (v1-verified). blocks 16..143: W1f -> bf16,
// permuted for 8-wave/64n A-in-regs: idx = ((w*16 + kk)*4 + ni)*512 + l*8 + e
//   n = 64w + 16ni + (l&15), d = 32kk + 8*(l>>4) + e
__global__ __launch_bounds__(512) void prep_kernel(
    const float* __restrict__ spk_in, const float* __restrict__ Wsp,
    const float* __restrict__ bsp,    const float* __restrict__ Wv,
    const float* __restrict__ bv,     const float* __restrict__ Wo,
    const float* __restrict__ bo,     const float* __restrict__ gma,
    const float* __restrict__ bta,    const float* __restrict__ Wg1,
    const float* __restrict__ bg1,
    float* __restrict__ attnn, float* __restrict__ biasb,
    unsigned short* __restrict__ w1fx)
{
  int tid = threadIdx.x;
  int blk = blockIdx.x;

  if (blk >= 16) {                    // ---- W1f -> bf16, permuted ----
    #pragma unroll
    for (int i = 0; i < 4; ++i) {
      int idx = (blk - 16) * 2048 + i * 512 + tid;
      int e  = idx & 7;
      int l  = (idx >> 3) & 63;
      int ni = (idx >> 9) & 3;
      int kk = (idx >> 11) & 15;
      int w  = (idx >> 15) & 7;
      int n = w * 64 + ni * 16 + (l & 15);
      int d = kk * 32 + (l >> 4) * 8 + e;
      w1fx[idx] = f2bf(Wg1[n * 1024 + d]);
    }
    return;
  }

  int b = blk;
  __shared__ __attribute__((aligned(16))) float s_spk[256];
  __shared__ __attribute__((aligned(16))) float s_x[512];
  __shared__ __attribute__((aligned(16))) float s_y[512];
  __shared__ float red[512];

  float se = (tid < 256) ? spk_in[b * 256 + tid] : 0.f;
  red[tid] = se * se;
  __syncthreads();
  for (int s = 256; s > 0; s >>= 1) {
    if (tid < s) red[tid] += red[tid + s];
    __syncthreads();
  }
  float scale = 1.f / fmaxf(sqrtf(red[0]), 1e-12f);
  if (tid < 256) s_spk[tid] = se * scale;
  __syncthreads();

  {
    const float* wr = Wsp + (size_t)tid * 256;
    f32x4 a4 = {0.f, 0.f, 0.f, 0.f};
    #pragma unroll 8
    for (int s2 = 0; s2 < 256; s2 += 4)
      a4 += (*(const f32x4*)(wr + s2)) * (*(const f32x4*)(s_spk + s2));
    s_x[tid] = a4[0] + a4[1] + a4[2] + a4[3] + bsp[tid];
  }
  __syncthreads();

  {
    const float* wr = Wv + (size_t)tid * 512;
    f32x4 a4 = {0.f, 0.f, 0.f, 0.f};
    #pragma unroll 8
    for (int s2 = 0; s2 < 512; s2 += 4)
      a4 += (*(const f32x4*)(wr + s2)) * (*(const f32x4*)(s_x + s2));
    s_y[tid] = a4[0] + a4[1] + a4[2] + a4[3] + bv[tid];
  }
  __syncthreads();

  float attnv;
  {
    const float* wr = Wo + (size_t)tid * 512;
    f32x4 a4 = {0.f, 0.f, 0.f, 0.f};
    #pragma unroll 8
    for (int s2 = 0; s2 < 512; s2 += 4)
      a4 += (*(const f32x4*)(wr + s2)) * (*(const f32x4*)(s_y + s2));
    attnv = a4[0] + a4[1] + a4[2] + a4[3] + bo[tid];
  }

  red[tid] = attnv;
  __syncthreads();
  for (int s = 256; s > 0; s >>= 1) {
    if (tid < s) red[tid] += red[tid + s];
    __syncthreads();
  }
  float mu = red[0] * (1.f / 512.f);
  __syncthreads();
  float dv = attnv - mu;
  red[tid] = dv * dv;
  __syncthreads();
  for (int s = 256; s > 0; s >>= 1) {
    if (tid < s) red[tid] += red[tid + s];
    __syncthreads();
  }
  float var = red[0] * (1.f / 512.f);
  float an = dv * rsqrtf(var + 1e-5f) * gma[tid] + bta[tid];
  s_x[tid] = an;
  attnn[b * 512 + tid] = an;
  __syncthreads();

  {
    const float* wr = Wg1 + (size_t)tid * 1024 + 512;
    f32x4 a4 = {0.f, 0.f, 0.f, 0.f};
    #pragma unroll 8
    for (int s2 = 0; s2 < 512; s2 += 4)
      a4 += (*(const f32x4*)(wr + s2)) * (*(const f32x4*)(s_x + s2));
    biasb[b * 512 + tid] = a4[0] + a4[1] + a4[2] + a4[3] + bg1[tid];
  }
}

// ---------------- main kernel ----------------
// 256 blocks x 512 thr (8 waves, 1 block/CU). b = blk>>4, tseg = blk&15.
// 16 tiles of 32t. A in regs; F (f32, 64KB) single-buffered via DMA; Bt (bf16
// swizzled, 32KB) single-buffered.
__global__ __launch_bounds__(512, 1) void main_kernel(
    const float* __restrict__ feat, const unsigned short* __restrict__ w1fx,
    const float* __restrict__ attnn, const float* __restrict__ biasb,
    const float* __restrict__ wg2p,  const float* __restrict__ bg2p,
    float* __restrict__ out)
{
  __shared__ __attribute__((aligned(16))) float F[16384];            // 64 KB
  __shared__ __attribute__((aligned(16))) unsigned short Bt[16384];  // 32 KB
  __shared__ __attribute__((aligned(16))) float s_attn[512];
  __shared__ float gpart[8 * 32];
  __shared__ float als[32];

  int tid = threadIdx.x;
  int l = tid & 63, w = tid >> 6;
  int b = blockIdx.x >> 4, tseg = blockIdx.x & 15;
  int t0base = tseg * 512;
  const char* featb = (const char*)(feat + (size_t)b * D_DIM * T_DIM);
  char* Fc = (char*)F;
  char* Bc = (char*)Bt;

  int a3 = l >> 3, l7 = l & 7;
  int g = l >> 4, cc = l & 15;
  int xsw = (cc & 7) << 4;

  // ---- A-slice into registers: wave w owns n in [64w, 64w+64) ----
  const unsigned short* apw = w1fx + (size_t)w * 32768;
  short8 af[4][16];
  #pragma unroll
  for (int kk = 0; kk < 16; ++kk)
    #pragma unroll
    for (int ni = 0; ni < 4; ++ni)
      af[ni][kk] = *(const short8*)(apw + (kk * 4 + ni) * 512 + l * 8);

  float bia[4][4], ww2[4][4];
  #pragma unroll
  for (int ni = 0; ni < 4; ++ni)
    #pragma unroll
    for (int rr = 0; rr < 4; ++rr) {
      int n = w * 64 + ni * 16 + g * 4 + rr;
      bia[ni][rr] = biasb[b * 512 + n];
      ww2[ni][rr] = wg2p[n];
    }
  s_attn[tid] = attnn[b * 512 + tid];
  float bg2v = bg2p[0];

  // DMA: wave w pulls its d in [64w,64w+64) x 32t; 8 instrs of 64 lanes x 16B.
  // lane l, instr q: d = 64w+8q+a3, t-quad = l7^a3^q (bank/bank-spread perm).
#define DMA(J) do {                                                         \
    _Pragma("unroll")                                                       \
    for (int q_ = 0; q_ < 8; ++q_) {                                        \
      int d_ = w * 64 + q_ * 8 + a3;                                        \
      int tp_ = l7 ^ a3 ^ q_;                                               \
      dma16(featb + (((size_t)d_) << 15) +                                  \
                ((size_t)(t0base + (J) * 32) << 2) + tp_ * 16,              \
            Fc + (w * 8 + q_) * 1024);                                      \
    }                                                                       \
    __builtin_amdgcn_sched_barrier(0);                                      \
  } while (0)

  DMA(0);

  int dq = tid >> 3;         // 0..63 ; dq&7 == the q that DMA'd this block
  int tqc = tid & 7, dq7 = dq & 7;

  #pragma unroll 1
  for (int j = 0; j < 16; ++j) {
    // top: quiesce LDS readers of Bt/als, then wait own DMA landed
    asm volatile("s_waitcnt lgkmcnt(0)" ::: "memory");
    __builtin_amdgcn_s_barrier();
    if (j == 0) asm volatile("s_waitcnt vmcnt(0)" ::: "memory");
    else        asm volatile("s_waitcnt vmcnt(32)" ::: "memory");
    __builtin_amdgcn_sched_barrier(0);

    // ---- convert: F (wave-local d-range) -> Bt bf16 swizzled [t][d] ----
    {
      f32x4 v[8];
      #pragma unroll
      for (int i = 0; i < 8; ++i)
        v[i] = *(const f32x4*)(Fc + (dq << 10) +
                               ((i * 8 + (tqc ^ i ^ dq7)) << 4));
      #pragma unroll
      for (int ii = 0; ii < 4; ++ii) {
        int t = tqc * 4 + ii;
        short8 wv;
        #pragma unroll
        for (int i = 0; i < 8; ++i) wv[i] = (short)f2bf(v[i][ii]);
        *(short8*)(Bc + (t << 10) + ((dq * 16) ^ ((t & 7) << 4))) = wv;
      }
    }
    asm volatile("s_waitcnt lgkmcnt(0)" ::: "memory");
    __builtin_amdgcn_s_barrier();
    __builtin_amdgcn_sched_barrier(0);

    // ---- next tile's DMA flies across GEMM+alpha+blend ----
    if (j < 15) DMA(j + 1);

    // ---- GEMM: pure LDS+MFMA; wave w -> n in [64w,64w+64), t in [0,32) ----
    f32x4 acc[4][2];
    #pragma unroll
    for (int ni = 0; ni < 4; ++ni) {
      acc[ni][0] = (f32x4){0.f, 0.f, 0.f, 0.f};
      acc[ni][1] = (f32x4){0.f, 0.f, 0.f, 0.f};
    }
    #pragma unroll
    for (int kk = 0; kk < 16; ++kk) {
      short8 bf0 = *(const short8*)(Bc + (cc << 10) + ((kk * 64 + g * 16) ^ xsw));
      short8 bf1 = *(const short8*)(Bc + ((16 + cc) << 10) + ((kk * 64 + g * 16) ^ xsw));
      #pragma unroll
      for (int ni = 0; ni < 4; ++ni) {
        acc[ni][0] = __builtin_amdgcn_mfma_f32_16x16x32_bf16(af[ni][kk], bf0, acc[ni][0], 0, 0, 0);
        acc[ni][1] = __builtin_amdgcn_mfma_f32_16x16x32_bf16(af[ni][kk], bf1, acc[ni][1], 0, 0, 0);
      }
    }
    // acc[ni][tg] lane l reg rr: h[n = 64w+16ni+4g+rr][t = 16tg+cc]

    // ---- alpha ----
    float p0 = 0.f, p1 = 0.f;
    #pragma unroll
    for (int ni = 0; ni < 4; ++ni)
      #pragma unroll
      for (int rr = 0; rr < 4; ++rr) {
        p0 += fmaxf(acc[ni][0][rr] + bia[ni][rr], 0.f) * ww2[ni][rr];
        p1 += fmaxf(acc[ni][1][rr] + bia[ni][rr], 0.f) * ww2[ni][rr];
      }
    p0 += __shfl_xor(p0, 16); p0 += __shfl_xor(p0, 32);
    p1 += __shfl_xor(p1, 16); p1 += __shfl_xor(p1, 32);
    if (l < 16) {
      gpart[w * 32 + l] = p0;
      gpart[w * 32 + 16 + l] = p1;
    }
    asm volatile("s_waitcnt lgkmcnt(0)" ::: "memory");
    __builtin_amdgcn_s_barrier();
    if (tid < 32) {
      float gs = bg2v;
      #pragma unroll
      for (int w2 = 0; w2 < 8; ++w2) gs += gpart[w2 * 32 + tid];
      als[tid] = 1.f / (1.f + expf(-gs));
    }
    asm volatile("s_waitcnt lgkmcnt(0)" ::: "memory");
    __builtin_amdgcn_s_barrier();

    // ---- blend: out[b,d,t] = a*f + (1-a)*attn_n[d]; 32 plain stores ----
    {
      int tl = tid & 31, dgb = tid >> 5;     // t row; d-group of 32
      float al = als[tl], om = 1.f - al;
      float* op = out + (size_t)b * D_DIM * T_DIM + t0base + j * 32 + tl;
      int rbase = tl << 10, rsw = (tl & 7) << 4;
      #pragma unroll
      for (int h = 0; h < 4; ++h) {
        short8 fv = *(const short8*)(Bc + rbase + ((dgb * 64 + h * 16) ^ rsw));
        int d0 = dgb * 32 + h * 8;
        f32x4 an0 = *(const f32x4*)(&s_attn[d0]);
        f32x4 an1 = *(const f32x4*)(&s_attn[d0 + 4]);
        #pragma unroll
        for (int e = 0; e < 4; ++e) {
          op[(size_t)(d0 + e) * T_DIM]     = al * bf2f((unsigned short)fv[e])     + om * an0[e];
          op[(size_t)(d0 + 4 + e) * T_DIM] = al * bf2f((unsigned short)fv[e + 4]) + om * an1[e];
        }
      }
    }
  }
#undef DMA
}

extern "C" void kernel_launch(void* const* d_in, const int* in_sizes, int n_in,
                              void* d_out, int out_size, void* d_ws, size_t ws_size,
                              hipStream_t stream) {
  const float* features = (const float*)d_in[0];
  const float* spk      = (const float*)d_in[1];
  const float* Wsp      = (const float*)d_in[2];
  const float* bsp      = (const float*)d_in[3];
  const float* Wv       = (const float*)d_in[4];
  const float* bv       = (const float*)d_in[5];
  const float* Wo       = (const float*)d_in[6];
  const float* bo       = (const float*)d_in[7];
  const float* gma      = (const float*)d_in[8];
  const float* bta      = (const float*)d_in[9];
  const float* Wg1      = (const float*)d_in[10];
  const float* bg1      = (const float*)d_in[11];
  const float* Wg2      = (const float*)d_in[12];
  const float* bg2      = (const float*)d_in[13];
  float* out = (float*)d_out;

  // ws: attnn[8192] f32 | biasb[8192] f32 | w1fx[262144] bf16 (permuted)
  float* attnn = (float*)d_ws;
  float* biasb = attnn + 8192;
  unsigned short* w1fx = (unsigned short*)(biasb + 8192);

  prep_kernel<<<144, 512, 0, stream>>>(spk, Wsp, bsp, Wv, bv, Wo, bo, gma, bta,
                                       Wg1, bg1, attnn, biasb, w1fx);
  main_kernel<<<256, 512, 0, stream>>>(features, w1fx, attnn, biasb, Wg2, bg2, out);
}

// Round 12
// 288.848 us; speedup vs baseline: 1.6941x; 1.6941x over previous
//
#include <hip/hip_runtime.h>

// SpeakerCrossAttention on MI355X (gfx950) — v12: three simple kernels.
//   prep   : per-batch chain -> attnn/biasb; W1f -> bf16 permuted (v11-verified)
//   alpha2 : v5's alpha kernel + PERMUTED-CONTIGUOUS A loads (the fix) +
//            direct alpha->global write (2 barriers total)
//   blend  : v6's ILP blend (verified) + NT feature loads
// Key lesson from v1..v11: GEMM phases were A-request-bound (scattered af =
// 8192 L2 line-requests/block ~= 13.6us/block); permuted A = 64 requests.
// Register prefetch & A-in-regs are impossible (512KB VGPR file/CU).

typedef __attribute__((ext_vector_type(8))) short short8;     // 8 bf16 = 16B
typedef __attribute__((ext_vector_type(4))) unsigned short ushort4v;
typedef __attribute__((ext_vector_type(4))) float f32x4;

#define T_DIM 8192
#define D_DIM 512

__device__ __forceinline__ unsigned short f2bf(float x) {  // RTNE f32 -> bf16
  unsigned u = __builtin_bit_cast(unsigned, x);
  u = (u + 0x7fffu + ((u >> 16) & 1u)) >> 16;
  return (unsigned short)u;
}

// ---------------- prep kernel (v11-verified permutation) ----------------
// blocks 0..15: per-batch chain. blocks 16..143: W1f -> bf16 permuted:
//   idx = ((w*16 + kk)*4 + ni)*512 + l*8 + e
//   n = 64w + 16ni + (l&15), d = 32kk + 8*(l>>4) + e
__global__ __launch_bounds__(512) void prep_kernel(
    const float* __restrict__ spk_in, const float* __restrict__ Wsp,
    const float* __restrict__ bsp,    const float* __restrict__ Wv,
    const float* __restrict__ bv,     const float* __restrict__ Wo,
    const float* __restrict__ bo,     const float* __restrict__ gma,
    const float* __restrict__ bta,    const float* __restrict__ Wg1,
    const float* __restrict__ bg1,
    float* __restrict__ attnn, float* __restrict__ biasb,
    unsigned short* __restrict__ w1fx)
{
  int tid = threadIdx.x;
  int blk = blockIdx.x;

  if (blk >= 16) {
    #pragma unroll
    for (int i = 0; i < 4; ++i) {
      int idx = (blk - 16) * 2048 + i * 512 + tid;
      int e  = idx & 7;
      int l  = (idx >> 3) & 63;
      int ni = (idx >> 9) & 3;
      int kk = (idx >> 11) & 15;
      int w  = (idx >> 15) & 7;
      int n = w * 64 + ni * 16 + (l & 15);
      int d = kk * 32 + (l >> 4) * 8 + e;
      w1fx[idx] = f2bf(Wg1[n * 1024 + d]);
    }
    return;
  }

  int b = blk;
  __shared__ __attribute__((aligned(16))) float s_spk[256];
  __shared__ __attribute__((aligned(16))) float s_x[512];
  __shared__ __attribute__((aligned(16))) float s_y[512];
  __shared__ float red[512];

  float se = (tid < 256) ? spk_in[b * 256 + tid] : 0.f;
  red[tid] = se * se;
  __syncthreads();
  for (int s = 256; s > 0; s >>= 1) {
    if (tid < s) red[tid] += red[tid + s];
    __syncthreads();
  }
  float scale = 1.f / fmaxf(sqrtf(red[0]), 1e-12f);
  if (tid < 256) s_spk[tid] = se * scale;
  __syncthreads();

  {
    const float* wr = Wsp + (size_t)tid * 256;
    f32x4 a4 = {0.f, 0.f, 0.f, 0.f};
    #pragma unroll 8
    for (int s2 = 0; s2 < 256; s2 += 4)
      a4 += (*(const f32x4*)(wr + s2)) * (*(const f32x4*)(s_spk + s2));
    s_x[tid] = a4[0] + a4[1] + a4[2] + a4[3] + bsp[tid];
  }
  __syncthreads();

  {
    const float* wr = Wv + (size_t)tid * 512;
    f32x4 a4 = {0.f, 0.f, 0.f, 0.f};
    #pragma unroll 8
    for (int s2 = 0; s2 < 512; s2 += 4)
      a4 += (*(const f32x4*)(wr + s2)) * (*(const f32x4*)(s_x + s2));
    s_y[tid] = a4[0] + a4[1] + a4[2] + a4[3] + bv[tid];
  }
  __syncthreads();

  float attnv;
  {
    const float* wr = Wo + (size_t)tid * 512;
    f32x4 a4 = {0.f, 0.f, 0.f, 0.f};
    #pragma unroll 8
    for (int s2 = 0; s2 < 512; s2 += 4)
      a4 += (*(const f32x4*)(wr + s2)) * (*(const f32x4*)(s_y + s2));
    attnv = a4[0] + a4[1] + a4[2] + a4[3] + bo[tid];
  }

  red[tid] = attnv;
  __syncthreads();
  for (int s = 256; s > 0; s >>= 1) {
    if (tid < s) red[tid] += red[tid + s];
    __syncthreads();
  }
  float mu = red[0] * (1.f / 512.f);
  __syncthreads();
  float dv = attnv - mu;
  red[tid] = dv * dv;
  __syncthreads();
  for (int s = 256; s > 0; s >>= 1) {
    if (tid < s) red[tid] += red[tid + s];
    __syncthreads();
  }
  float var = red[0] * (1.f / 512.f);
  float an = dv * rsqrtf(var + 1e-5f) * gma[tid] + bta[tid];
  s_x[tid] = an;
  attnn[b * 512 + tid] = an;
  __syncthreads();

  {
    const float* wr = Wg1 + (size_t)tid * 1024 + 512;
    f32x4 a4 = {0.f, 0.f, 0.f, 0.f};
    #pragma unroll 8
    for (int s2 = 0; s2 < 512; s2 += 4)
      a4 += (*(const f32x4*)(wr + s2)) * (*(const f32x4*)(s_x + s2));
    biasb[b * 512 + tid] = a4[0] + a4[1] + a4[2] + a4[3] + bg1[tid];
  }
}

// ---------------- alpha kernel ----------------
// 2048 blocks (b = blk>>7, t0 = (blk&127)*64), 512 thr / 8 waves.
// Wave w: n in [64w, 64w+64). LDS 71.5KB -> 2 blocks/CU; VGPR ~110 -> resident.
__global__ __launch_bounds__(512) void alpha_kernel(
    const float* __restrict__ feat, const unsigned short* __restrict__ w1fx,
    const float* __restrict__ biasb, const float* __restrict__ wg2p,
    const float* __restrict__ bg2p,  float* __restrict__ alpha_out)
{
  __shared__ __attribute__((aligned(16))) unsigned short S[64 * 512]; // 64KB swz
  __shared__ __attribute__((aligned(16))) float s_bias[512];
  __shared__ __attribute__((aligned(16))) float s_wg2[512];
  __shared__ __attribute__((aligned(16))) float gpart[64 * 8];        // [t][w]

  int tid = threadIdx.x;
  int b  = blockIdx.x >> 7;
  int t0 = (blockIdx.x & 127) << 6;
  const float* fb = feat + (size_t)b * D_DIM * T_DIM + t0;
  char* Sb = (char*)S;

  // ---- stage (v5-verified): thread (mt,mk) loads 4t x 16d; loads first ----
  int mt = tid & 15, mk = tid >> 4;      // mk 0..31
  int tt = mt * 4;

  f32x4 r[16];
  #pragma unroll
  for (int it = 0; it < 2; ++it) {
    int k0 = mk * 8 + it * 256;
    #pragma unroll
    for (int q = 0; q < 8; ++q)
      r[it * 8 + q] = __builtin_nontemporal_load(
          (const f32x4*)(fb + (size_t)(k0 + q) * T_DIM + tt));
  }
  s_bias[tid] = biasb[b * 512 + tid];
  s_wg2[tid]  = wg2p[tid];
  __builtin_amdgcn_sched_barrier(0);     // all 16 loads issued before commits

  #pragma unroll
  for (int it = 0; it < 2; ++it) {
    int kbyte = (mk * 8 + it * 256) * 2;
    #pragma unroll
    for (int i = 0; i < 4; ++i) {
      short8 wv;
      #pragma unroll
      for (int q = 0; q < 8; ++q)
        wv[q] = (short)f2bf(r[it * 8 + q][i]);
      int row = tt + i;
      int byte = (row << 10) + kbyte;
      byte ^= (row & 7) << 4;            // bank swizzle
      *(short8*)(Sb + byte) = wv;        // ds_write_b128
    }
  }
  __syncthreads();

  // ---- GEMM: h^T = W1f * F^T, PERMUTED-CONTIGUOUS af (the v12 fix) ----
  int l = tid & 63, w = tid >> 6;
  int g = l >> 4, cc = l & 15;
  int n0w = w * 64;
  const unsigned short* apw = w1fx + (size_t)w * 32768;  // wave's A slice
  int xsw = (cc & 7) << 4;
  int bb0 = (cc << 10) + g * 16;

  f32x4 acc[4][4];
  #pragma unroll
  for (int i = 0; i < 4; ++i)
    #pragma unroll
    for (int j = 0; j < 4; ++j)
      acc[i][j] = (f32x4){0.f, 0.f, 0.f, 0.f};

  #pragma unroll 2
  for (int kk = 0; kk < 16; ++kk) {
    short8 af[4], bf[4];
    #pragma unroll
    for (int ni = 0; ni < 4; ++ni)
      af[ni] = *(const short8*)(apw + (kk * 4 + ni) * 512 + l * 8);  // 1KB contig
    #pragma unroll
    for (int tg = 0; tg < 4; ++tg)
      bf[tg] = *(const short8*)(Sb + ((bb0 + tg * 16384 + kk * 64) ^ xsw));
    #pragma unroll
    for (int ni = 0; ni < 4; ++ni)
      #pragma unroll
      for (int tg = 0; tg < 4; ++tg)
        acc[ni][tg] = __builtin_amdgcn_mfma_f32_16x16x32_bf16(
            af[ni], bf[tg], acc[ni][tg], 0, 0, 0);
  }
  // lane l, reg rr of acc[ni][tg]: h[n = n0w+16ni+4g+rr][t = 16tg+cc]

  // ---- alpha partials ----
  float p0 = 0.f, p1 = 0.f, p2 = 0.f, p3 = 0.f;
  #pragma unroll
  for (int ni = 0; ni < 4; ++ni) {
    #pragma unroll
    for (int rr = 0; rr < 4; ++rr) {
      int n = n0w + 16 * ni + 4 * g + rr;
      float bb = s_bias[n], ww = s_wg2[n];
      p0 += fmaxf(acc[ni][0][rr] + bb, 0.f) * ww;
      p1 += fmaxf(acc[ni][1][rr] + bb, 0.f) * ww;
      p2 += fmaxf(acc[ni][2][rr] + bb, 0.f) * ww;
      p3 += fmaxf(acc[ni][3][rr] + bb, 0.f) * ww;
    }
  }
  p0 += __shfl_xor(p0, 16); p0 += __shfl_xor(p0, 32);
  p1 += __shfl_xor(p1, 16); p1 += __shfl_xor(p1, 32);
  p2 += __shfl_xor(p2, 16); p2 += __shfl_xor(p2, 32);
  p3 += __shfl_xor(p3, 16); p3 += __shfl_xor(p3, 32);
  if (l < 16) {
    gpart[( 0 + l) * 8 + w] = p0;
    gpart[(16 + l) * 8 + w] = p1;
    gpart[(32 + l) * 8 + w] = p2;
    gpart[(48 + l) * 8 + w] = p3;
  }
  __syncthreads();
  if (tid < 64) {
    f32x4 a0 = *(const f32x4*)(&gpart[tid * 8]);
    f32x4 a1 = *(const f32x4*)(&gpart[tid * 8 + 4]);
    float gs = bg2p[0] + a0[0] + a0[1] + a0[2] + a0[3]
                       + a1[0] + a1[1] + a1[2] + a1[3];
    alpha_out[(size_t)b * T_DIM + t0 + tid] = 1.f / (1.f + __expf(-gs));
  }
}

// ---------------- blend kernel (v6-verified, NT feature loads) ----------------
__global__ __launch_bounds__(256) void blend_kernel(
    const float* __restrict__ feat,  const float* __restrict__ alpha,
    const float* __restrict__ attnn, float* __restrict__ out)
{
  int u0 = blockIdx.x * 256 + threadIdx.x;
  const int NU = 16 * 128 * 2048;           // 4,194,304 units of 4d x 4t
  const int stride = 2048 * 256;
  #pragma unroll 2
  for (int u = u0; u < NU; u += stride) {
    int b  = u >> 18;
    int dq = (u >> 11) & 127;
    int t  = (u & 2047) << 2;
    int d0 = dq << 2;
    size_t fbase = ((size_t)(b * 512 + d0) << 13) + t;
    f32x4 a  = *(const f32x4*)(alpha + ((size_t)b << 13) + t);
    f32x4 an = *(const f32x4*)(attnn + b * 512 + d0);
    f32x4 f0 = __builtin_nontemporal_load((const f32x4*)(feat + fbase));
    f32x4 f1 = __builtin_nontemporal_load((const f32x4*)(feat + fbase + 8192));
    f32x4 f2 = __builtin_nontemporal_load((const f32x4*)(feat + fbase + 16384));
    f32x4 f3 = __builtin_nontemporal_load((const f32x4*)(feat + fbase + 24576));
    f32x4 o0, o1, o2, o3;
    #pragma unroll
    for (int j = 0; j < 4; ++j) {
      float om_a = 1.f - a[j];
      o0[j] = a[j] * f0[j] + om_a * an[0];
      o1[j] = a[j] * f1[j] + om_a * an[1];
      o2[j] = a[j] * f2[j] + om_a * an[2];
      o3[j] = a[j] * f3[j] + om_a * an[3];
    }
    __builtin_nontemporal_store(o0, (f32x4*)(out + fbase));
    __builtin_nontemporal_store(o1, (f32x4*)(out + fbase + 8192));
    __builtin_nontemporal_store(o2, (f32x4*)(out + fbase + 16384));
    __builtin_nontemporal_store(o3, (f32x4*)(out + fbase + 24576));
  }
}

extern "C" void kernel_launch(void* const* d_in, const int* in_sizes, int n_in,
                              void* d_out, int out_size, void* d_ws, size_t ws_size,
                              hipStream_t stream) {
  const float* features = (const float*)d_in[0];
  const float* spk      = (const float*)d_in[1];
  const float* Wsp      = (const float*)d_in[2];
  const float* bsp      = (const float*)d_in[3];
  const float* Wv       = (const float*)d_in[4];
  const float* bv       = (const float*)d_in[5];
  const float* Wo       = (const float*)d_in[6];
  const float* bo       = (const float*)d_in[7];
  const float* gma      = (const float*)d_in[8];
  const float* bta      = (const float*)d_in[9];
  const float* Wg1      = (const float*)d_in[10];
  const float* bg1      = (const float*)d_in[11];
  const float* Wg2      = (const float*)d_in[12];
  const float* bg2      = (const float*)d_in[13];
  float* out = (float*)d_out;

  // ws: attnn[8192] f32 | biasb[8192] f32 | alpha[131072] f32 | w1fx[262144] bf16
  float* attnn = (float*)d_ws;
  float* biasb = attnn + 8192;
  float* alpha = biasb + 8192;
  unsigned short* w1fx = (unsigned short*)(alpha + 131072);

  prep_kernel<<<144, 512, 0, stream>>>(spk, Wsp, bsp, Wv, bv, Wo, bo, gma, bta,
                                       Wg1, bg1, attnn, biasb, w1fx);
  alpha_kernel<<<2048, 512, 0, stream>>>(features, w1fx, biasb, Wg2, bg2, alpha);
  blend_kernel<<<2048, 256, 0, stream>>>(features, alpha, attnn, out);
}

// Round 13
// 239.923 us; speedup vs baseline: 2.0396x; 1.2039x over previous
//
#include <hip/hip_runtime.h>

// SpeakerCrossAttention on MI355X (gfx950) — v13: fused alpha+blend, one pass.
//   prep : per-batch chain -> attnn/biasb; W1f -> bf16 permuted (v11/v12-verified)
//   main : v12's alpha kernel (verified: swizzled staging, permuted-contiguous
//          A loads, 2-barrier GEMM) + v1-style blend from the staged LDS tile.
// Features read ONCE (256MB), out written once (256MB) => 512MB floor.
// vs v12 split (288us): saves the 256MB blend re-read + alpha round-trip +
// one launch. A-traffic 4MB/CU from L2 (~30us) hides under HBM streaming.

typedef __attribute__((ext_vector_type(8))) short short8;     // 8 bf16 = 16B
typedef __attribute__((ext_vector_type(4))) unsigned short ushort4v;
typedef __attribute__((ext_vector_type(4))) float f32x4;

#define T_DIM 8192
#define D_DIM 512

__device__ __forceinline__ unsigned short f2bf(float x) {  // RTNE f32 -> bf16
  unsigned u = __builtin_bit_cast(unsigned, x);
  u = (u + 0x7fffu + ((u >> 16) & 1u)) >> 16;
  return (unsigned short)u;
}
__device__ __forceinline__ float bf2f(unsigned short h) {
  return __builtin_bit_cast(float, ((unsigned)h) << 16);
}

// ---------------- prep kernel (v12-verified) ----------------
__global__ __launch_bounds__(512) void prep_kernel(
    const float* __restrict__ spk_in, const float* __restrict__ Wsp,
    const float* __restrict__ bsp,    const float* __restrict__ Wv,
    const float* __restrict__ bv,     const float* __restrict__ Wo,
    const float* __restrict__ bo,     const float* __restrict__ gma,
    const float* __restrict__ bta,    const float* __restrict__ Wg1,
    const float* __restrict__ bg1,
    float* __restrict__ attnn, float* __restrict__ biasb,
    unsigned short* __restrict__ w1fx)
{
  int tid = threadIdx.x;
  int blk = blockIdx.x;

  if (blk >= 16) {                    // W1f -> bf16 permuted:
    #pragma unroll                    // idx = ((w*16+kk)*4+ni)*512 + l*8 + e
    for (int i = 0; i < 4; ++i) {     // n = 64w+16ni+(l&15), d = 32kk+8(l>>4)+e
      int idx = (blk - 16) * 2048 + i * 512 + tid;
      int e  = idx & 7;
      int l  = (idx >> 3) & 63;
      int ni = (idx >> 9) & 3;
      int kk = (idx >> 11) & 15;
      int w  = (idx >> 15) & 7;
      int n = w * 64 + ni * 16 + (l & 15);
      int d = kk * 32 + (l >> 4) * 8 + e;
      w1fx[idx] = f2bf(Wg1[n * 1024 + d]);
    }
    return;
  }

  int b = blk;
  __shared__ __attribute__((aligned(16))) float s_spk[256];
  __shared__ __attribute__((aligned(16))) float s_x[512];
  __shared__ __attribute__((aligned(16))) float s_y[512];
  __shared__ float red[512];

  float se = (tid < 256) ? spk_in[b * 256 + tid] : 0.f;
  red[tid] = se * se;
  __syncthreads();
  for (int s = 256; s > 0; s >>= 1) {
    if (tid < s) red[tid] += red[tid + s];
    __syncthreads();
  }
  float scale = 1.f / fmaxf(sqrtf(red[0]), 1e-12f);
  if (tid < 256) s_spk[tid] = se * scale;
  __syncthreads();

  {
    const float* wr = Wsp + (size_t)tid * 256;
    f32x4 a4 = {0.f, 0.f, 0.f, 0.f};
    #pragma unroll 8
    for (int s2 = 0; s2 < 256; s2 += 4)
      a4 += (*(const f32x4*)(wr + s2)) * (*(const f32x4*)(s_spk + s2));
    s_x[tid] = a4[0] + a4[1] + a4[2] + a4[3] + bsp[tid];
  }
  __syncthreads();

  {
    const float* wr = Wv + (size_t)tid * 512;
    f32x4 a4 = {0.f, 0.f, 0.f, 0.f};
    #pragma unroll 8
    for (int s2 = 0; s2 < 512; s2 += 4)
      a4 += (*(const f32x4*)(wr + s2)) * (*(const f32x4*)(s_x + s2));
    s_y[tid] = a4[0] + a4[1] + a4[2] + a4[3] + bv[tid];
  }
  __syncthreads();

  float attnv;
  {
    const float* wr = Wo + (size_t)tid * 512;
    f32x4 a4 = {0.f, 0.f, 0.f, 0.f};
    #pragma unroll 8
    for (int s2 = 0; s2 < 512; s2 += 4)
      a4 += (*(const f32x4*)(wr + s2)) * (*(const f32x4*)(s_y + s2));
    attnv = a4[0] + a4[1] + a4[2] + a4[3] + bo[tid];
  }

  red[tid] = attnv;
  __syncthreads();
  for (int s = 256; s > 0; s >>= 1) {
    if (tid < s) red[tid] += red[tid + s];
    __syncthreads();
  }
  float mu = red[0] * (1.f / 512.f);
  __syncthreads();
  float dv = attnv - mu;
  red[tid] = dv * dv;
  __syncthreads();
  for (int s = 256; s > 0; s >>= 1) {
    if (tid < s) red[tid] += red[tid + s];
    __syncthreads();
  }
  float var = red[0] * (1.f / 512.f);
  float an = dv * rsqrtf(var + 1e-5f) * gma[tid] + bta[tid];
  s_x[tid] = an;
  attnn[b * 512 + tid] = an;
  __syncthreads();

  {
    const float* wr = Wg1 + (size_t)tid * 1024 + 512;
    f32x4 a4 = {0.f, 0.f, 0.f, 0.f};
    #pragma unroll 8
    for (int s2 = 0; s2 < 512; s2 += 4)
      a4 += (*(const f32x4*)(wr + s2)) * (*(const f32x4*)(s_x + s2));
    biasb[b * 512 + tid] = a4[0] + a4[1] + a4[2] + a4[3] + bg1[tid];
  }
}

// ---------------- fused main kernel ----------------
// 2048 blocks (b = blk>>7, t0 = (blk&127)*64), 512 thr / 8 waves, 2 blocks/CU.
__global__ __launch_bounds__(512) void main_kernel(
    const float* __restrict__ feat, const unsigned short* __restrict__ w1fx,
    const float* __restrict__ attnn, const float* __restrict__ biasb,
    const float* __restrict__ wg2p,  const float* __restrict__ bg2p,
    float* __restrict__ out)
{
  __shared__ __attribute__((aligned(16))) unsigned short S[64 * 512]; // 64KB swz
  __shared__ __attribute__((aligned(16))) float s_bias[512];
  __shared__ __attribute__((aligned(16))) float s_wg2[512];
  __shared__ __attribute__((aligned(16))) float s_attn[512];
  __shared__ __attribute__((aligned(16))) float gpart[64 * 8];        // [t][w]
  __shared__ float als[64];

  int tid = threadIdx.x;
  int b  = blockIdx.x >> 7;
  int t0 = (blockIdx.x & 127) << 6;
  const float* fb = feat + (size_t)b * D_DIM * T_DIM + t0;
  char* Sb = (char*)S;

  // ---- stage (v5/v12-verified): thread (mt,mk) loads 4t x 16d ----
  int mt = tid & 15, mk = tid >> 4;      // mk 0..31
  int tt = mt * 4;

  f32x4 r[16];
  #pragma unroll
  for (int it = 0; it < 2; ++it) {
    int k0 = mk * 8 + it * 256;
    #pragma unroll
    for (int q = 0; q < 8; ++q)
      r[it * 8 + q] = __builtin_nontemporal_load(
          (const f32x4*)(fb + (size_t)(k0 + q) * T_DIM + tt));
  }
  s_bias[tid] = biasb[b * 512 + tid];
  s_wg2[tid]  = wg2p[tid];
  s_attn[tid] = attnn[b * 512 + tid];
  __builtin_amdgcn_sched_barrier(0);     // all 16 loads issued before commits

  #pragma unroll
  for (int it = 0; it < 2; ++it) {
    int kbyte = (mk * 8 + it * 256) * 2;
    #pragma unroll
    for (int i = 0; i < 4; ++i) {
      short8 wv;
      #pragma unroll
      for (int q = 0; q < 8; ++q)
        wv[q] = (short)f2bf(r[it * 8 + q][i]);
      int row = tt + i;
      int byte = (row << 10) + kbyte;
      byte ^= (row & 7) << 4;            // bank swizzle
      *(short8*)(Sb + byte) = wv;        // ds_write_b128
    }
  }
  __syncthreads();

  // ---- GEMM (v12-verified): permuted-contiguous af ----
  int l = tid & 63, w = tid >> 6;
  int g = l >> 4, cc = l & 15;
  int n0w = w * 64;
  const unsigned short* apw = w1fx + (size_t)w * 32768;  // wave's A slice
  int xsw = (cc & 7) << 4;
  int bb0 = (cc << 10) + g * 16;

  f32x4 acc[4][4];
  #pragma unroll
  for (int i = 0; i < 4; ++i)
    #pragma unroll
    for (int j = 0; j < 4; ++j)
      acc[i][j] = (f32x4){0.f, 0.f, 0.f, 0.f};

  #pragma unroll 2
  for (int kk = 0; kk < 16; ++kk) {
    short8 af[4], bf[4];
    #pragma unroll
    for (int ni = 0; ni < 4; ++ni)
      af[ni] = *(const short8*)(apw + (kk * 4 + ni) * 512 + l * 8);  // 1KB contig
    #pragma unroll
    for (int tg = 0; tg < 4; ++tg)
      bf[tg] = *(const short8*)(Sb + ((bb0 + tg * 16384 + kk * 64) ^ xsw));
    #pragma unroll
    for (int ni = 0; ni < 4; ++ni)
      #pragma unroll
      for (int tg = 0; tg < 4; ++tg)
        acc[ni][tg] = __builtin_amdgcn_mfma_f32_16x16x32_bf16(
            af[ni], bf[tg], acc[ni][tg], 0, 0, 0);
  }
  // lane l, reg rr of acc[ni][tg]: h[n = n0w+16ni+4g+rr][t = 16tg+cc]

  // ---- alpha partials ----
  float p0 = 0.f, p1 = 0.f, p2 = 0.f, p3 = 0.f;
  #pragma unroll
  for (int ni = 0; ni < 4; ++ni) {
    #pragma unroll
    for (int rr = 0; rr < 4; ++rr) {
      int n = n0w + 16 * ni + 4 * g + rr;
      float bb = s_bias[n], ww = s_wg2[n];
      p0 += fmaxf(acc[ni][0][rr] + bb, 0.f) * ww;
      p1 += fmaxf(acc[ni][1][rr] + bb, 0.f) * ww;
      p2 += fmaxf(acc[ni][2][rr] + bb, 0.f) * ww;
      p3 += fmaxf(acc[ni][3][rr] + bb, 0.f) * ww;
    }
  }
  p0 += __shfl_xor(p0, 16); p0 += __shfl_xor(p0, 32);
  p1 += __shfl_xor(p1, 16); p1 += __shfl_xor(p1, 32);
  p2 += __shfl_xor(p2, 16); p2 += __shfl_xor(p2, 32);
  p3 += __shfl_xor(p3, 16); p3 += __shfl_xor(p3, 32);
  if (l < 16) {
    gpart[( 0 + l) * 8 + w] = p0;
    gpart[(16 + l) * 8 + w] = p1;
    gpart[(32 + l) * 8 + w] = p2;
    gpart[(48 + l) * 8 + w] = p3;
  }
  __syncthreads();
  if (tid < 64) {
    f32x4 a0 = *(const f32x4*)(&gpart[tid * 8]);
    f32x4 a1 = *(const f32x4*)(&gpart[tid * 8 + 4]);
    float gs = bg2p[0] + a0[0] + a0[1] + a0[2] + a0[3]
                       + a1[0] + a1[1] + a1[2] + a1[3];
    als[tid] = 1.f / (1.f + __expf(-gs));
  }
  __syncthreads();

  // ---- blend from LDS (v1-style, swizzled reads, NT stores) ----
  {
    int tl = tid & 63, gg = tid >> 6;    // tl: t row, gg: 0..7
    float al = als[tl], om = 1.f - al;
    float* ob = out + (size_t)b * D_DIM * T_DIM + t0 + tl;
    int rbase = tl << 10, rsw = (tl & 7) << 4;
    #pragma unroll 4
    for (int it = 0; it < 16; ++it) {
      int d0 = it * 32 + gg * 4;
      ushort4v fv = *(const ushort4v*)(Sb + rbase + ((d0 * 2) ^ rsw));
      f32x4 an = *(const f32x4*)(&s_attn[d0]);
      #pragma unroll
      for (int i = 0; i < 4; ++i)
        __builtin_nontemporal_store(al * bf2f(fv[i]) + om * an[i],
                                    ob + (size_t)(d0 + i) * T_DIM);
    }
  }
}

extern "C" void kernel_launch(void* const* d_in, const int* in_sizes, int n_in,
                              void* d_out, int out_size, void* d_ws, size_t ws_size,
                              hipStream_t stream) {
  const float* features = (const float*)d_in[0];
  const float* spk      = (const float*)d_in[1];
  const float* Wsp      = (const float*)d_in[2];
  const float* bsp      = (const float*)d_in[3];
  const float* Wv       = (const float*)d_in[4];
  const float* bv       = (const float*)d_in[5];
  const float* Wo       = (const float*)d_in[6];
  const float* bo       = (const float*)d_in[7];
  const float* gma      = (const float*)d_in[8];
  const float* bta      = (const float*)d_in[9];
  const float* Wg1      = (const float*)d_in[10];
  const float* bg1      = (const float*)d_in[11];
  const float* Wg2      = (const float*)d_in[12];
  const float* bg2      = (const float*)d_in[13];
  float* out = (float*)d_out;

  // ws: attnn[8192] f32 | biasb[8192] f32 | w1fx[262144] bf16 (permuted)
  float* attnn = (float*)d_ws;
  float* biasb = attnn + 8192;
  unsigned short* w1fx = (unsigned short*)(biasb + 8192);

  prep_kernel<<<144, 512, 0, stream>>>(spk, Wsp, bsp, Wv, bv, Wo, bo, gma, bta,
                                       Wg1, bg1, attnn, biasb, w1fx);
  main_kernel<<<2048, 512, 0, stream>>>(features, w1fx, attnn, biasb, Wg2, bg2, out);
}